// Round 6
// baseline (594.691 us; speedup 1.0000x reference)
//
#include <hip/hip_runtime.h>
#include <math.h>

#define NEG_CONST (-9000000000000000.0f)
#define SCARE 11.313708498984761f  // sqrt(128)

#define DPP_XOR1  0xB1   // quad_perm [1,0,3,2]
#define DPP_XOR2  0x4E   // quad_perm [2,3,0,1]
#define DPP_XOR7  0x141  // row_half_mirror
#define DPP_XOR15 0x140  // row_mirror

template<int CTRL>
__device__ __forceinline__ float dpp_add(float x) {
    int yi = __builtin_amdgcn_update_dpp(0, __float_as_int(x), CTRL, 0xF, 0xF, true);
    return x + __int_as_float(yi);
}
template<int CTRL>
__device__ __forceinline__ float dpp_max(float x) {
    int yi = __builtin_amdgcn_update_dpp(0, __float_as_int(x), CTRL, 0xF, 0xF, true);
    return fmaxf(x, __int_as_float(yi));
}

__device__ __forceinline__ void wave_lds_fence() {
    __builtin_amdgcn_wave_barrier();
    asm volatile("s_waitcnt lgkmcnt(0)" ::: "memory");
    __builtin_amdgcn_wave_barrier();
}
__device__ __forceinline__ void wave_vm_fence() {
    __builtin_amdgcn_wave_barrier();
    asm volatile("s_waitcnt vmcnt(0) lgkmcnt(0)" ::: "memory");
    __builtin_amdgcn_wave_barrier();
}

// ---- kernel 1: y=0: QKt = Q @ K^T ; y=1: VV = V @ V  (grid (16,2)) ----
__global__ __launch_bounds__(256) void small_mm_a(const float* __restrict__ Q,
                                                  const float* __restrict__ K,
                                                  const float* __restrict__ V,
                                                  float* __restrict__ QKt,
                                                  float* __restrict__ VV) {
    int r  = blockIdx.x * 8 + (threadIdx.x >> 5);
    int c0 = (threadIdx.x & 31) * 4;
    float a0 = 0.f, a1 = 0.f, a2 = 0.f, a3 = 0.f;
    if (blockIdx.y == 0) {
        for (int k = 0; k < 128; k += 4) {
            float4 q  = *reinterpret_cast<const float4*>(&Q[r * 128 + k]);
            float4 k0 = *reinterpret_cast<const float4*>(&K[(c0 + 0) * 128 + k]);
            float4 k1 = *reinterpret_cast<const float4*>(&K[(c0 + 1) * 128 + k]);
            float4 k2 = *reinterpret_cast<const float4*>(&K[(c0 + 2) * 128 + k]);
            float4 k3 = *reinterpret_cast<const float4*>(&K[(c0 + 3) * 128 + k]);
            a0 += q.x*k0.x + q.y*k0.y + q.z*k0.z + q.w*k0.w;
            a1 += q.x*k1.x + q.y*k1.y + q.z*k1.z + q.w*k1.w;
            a2 += q.x*k2.x + q.y*k2.y + q.z*k2.z + q.w*k2.w;
            a3 += q.x*k3.x + q.y*k3.y + q.z*k3.z + q.w*k3.w;
        }
        float4 o = {a0, a1, a2, a3};
        *reinterpret_cast<float4*>(&QKt[r * 128 + c0]) = o;
    } else {
        for (int k = 0; k < 128; ++k) {
            float a = V[r * 128 + k];
            float4 b = *reinterpret_cast<const float4*>(&V[k * 128 + c0]);
            a0 += a * b.x; a1 += a * b.y; a2 += a * b.z; a3 += a * b.w;
        }
        float4 o = {a0, a1, a2, a3};
        *reinterpret_cast<float4*>(&VV[r * 128 + c0]) = o;
    }
}

// ---- kernel 2: MT = QKt @ V^T  (grid 16) ----
__global__ __launch_bounds__(256) void small_mm_b(const float* __restrict__ QKt,
                                                  const float* __restrict__ V,
                                                  float* __restrict__ MT) {
    int r  = blockIdx.x * 8 + (threadIdx.x >> 5);
    int c0 = (threadIdx.x & 31) * 4;
    float a0 = 0.f, a1 = 0.f, a2 = 0.f, a3 = 0.f;
    for (int k = 0; k < 128; k += 4) {
        float4 q  = *reinterpret_cast<const float4*>(&QKt[r * 128 + k]);
        float4 k0 = *reinterpret_cast<const float4*>(&V[(c0 + 0) * 128 + k]);
        float4 k1 = *reinterpret_cast<const float4*>(&V[(c0 + 1) * 128 + k]);
        float4 k2 = *reinterpret_cast<const float4*>(&V[(c0 + 2) * 128 + k]);
        float4 k3 = *reinterpret_cast<const float4*>(&V[(c0 + 3) * 128 + k]);
        a0 += q.x*k0.x + q.y*k0.y + q.z*k0.z + q.w*k0.w;
        a1 += q.x*k1.x + q.y*k1.y + q.z*k1.z + q.w*k1.w;
        a2 += q.x*k2.x + q.y*k2.y + q.z*k2.z + q.w*k2.w;
        a3 += q.x*k3.x + q.y*k3.y + q.z*k3.z + q.w*k3.w;
    }
    float4 o = {a0, a1, a2, a3};
    *reinterpret_cast<float4*>(&MT[r * 128 + c0]) = o;
}

// ---- kernel 3: projections; y=0: G[:,128:256]=x@QKt (+pack x into G[:,0:128]);
//      y=1: u=x@MT; y=2: xV=x@V.  128x128 tile, 8x8 per thread ----
__global__ __launch_bounds__(256) void proj_gemm(
    const float* __restrict__ x,
    const float* __restrict__ W0, const float* __restrict__ W1,
    const float* __restrict__ W2,
    float* __restrict__ G, float* __restrict__ O1, float* __restrict__ O2,
    int n)
{
    __shared__ __align__(16) float xs[32][132];  // [k][row] (transposed)
    __shared__ __align__(16) float ws[32][132];  // [k][col]

    const float* Wsel[3] = {W0, W1, W2};
    float*       Osel[3] = {G, O1, O2};
    const int    osr[3]  = {256, 128, 128};
    const int    oof[3]  = {128, 0, 0};
    int yb = blockIdx.y;
    const float* W = Wsel[yb];
    float*       O = Osel[yb];
    int ostride = osr[yb];
    int ooff = oof[yb];
    int row0 = blockIdx.x * 128;
    int tid = threadIdx.x;
    int tr = tid >> 4, tc = tid & 15;

    float acc[8][8] = {};
    for (int kk = 0; kk < 128; kk += 32) {
        #pragma unroll
        for (int it = 0; it < 4; ++it) {
            int id = tid + it * 256;
            int r = id >> 3;
            int f = id & 7;
            int grow = row0 + r;
            float4 v = (grow < n)
                ? *reinterpret_cast<const float4*>(&x[(size_t)grow * 128 + kk + f * 4])
                : make_float4(0.f, 0.f, 0.f, 0.f);
            xs[f * 4 + 0][r] = v.x; xs[f * 4 + 1][r] = v.y;
            xs[f * 4 + 2][r] = v.z; xs[f * 4 + 3][r] = v.w;
            if (yb == 0 && grow < n)
                *reinterpret_cast<float4*>(&G[(size_t)grow * 256 + kk + f * 4]) = v;
        }
        #pragma unroll
        for (int it = 0; it < 4; ++it) {
            int id = tid + it * 256;
            int k = id >> 5;
            int c4 = id & 31;
            *reinterpret_cast<float4*>(&ws[k][c4 * 4]) =
                *reinterpret_cast<const float4*>(&W[(size_t)(kk + k) * 128 + c4 * 4]);
        }
        __syncthreads();
        #pragma unroll 4
        for (int k = 0; k < 32; ++k) {
            float4 a0 = *reinterpret_cast<const float4*>(&xs[k][tr * 8]);
            float4 a1 = *reinterpret_cast<const float4*>(&xs[k][tr * 8 + 4]);
            float4 b0 = *reinterpret_cast<const float4*>(&ws[k][tc * 8]);
            float4 b1 = *reinterpret_cast<const float4*>(&ws[k][tc * 8 + 4]);
            float av[8] = {a0.x, a0.y, a0.z, a0.w, a1.x, a1.y, a1.z, a1.w};
            float bv[8] = {b0.x, b0.y, b0.z, b0.w, b1.x, b1.y, b1.z, b1.w};
            #pragma unroll
            for (int i2 = 0; i2 < 8; ++i2)
                #pragma unroll
                for (int j2 = 0; j2 < 8; ++j2)
                    acc[i2][j2] += av[i2] * bv[j2];
        }
        __syncthreads();
    }
    #pragma unroll
    for (int i2 = 0; i2 < 8; ++i2) {
        int grow = row0 + tr * 8 + i2;
        if (grow < n) {
            float4 o0 = {acc[i2][0], acc[i2][1], acc[i2][2], acc[i2][3]};
            float4 o1 = {acc[i2][4], acc[i2][5], acc[i2][6], acc[i2][7]};
            *reinterpret_cast<float4*>(&O[(size_t)grow * ostride + ooff + tc * 8])     = o0;
            *reinterpret_cast<float4*>(&O[(size_t)grow * ostride + ooff + tc * 8 + 4]) = o1;
        }
    }
}

// ---- kernel 4: per-node attention, 1 WAVE = 1 BLOCK = 1 node ----
// G[i] = [x[i](128) | xQK[i](128)] -> each neighbor gather is 1KB contiguous.
// x-half -> LDS via global_load_lds (line-transposed on the GLOBAL src addr);
// xQK-half -> A registers. Output uses y = sum_k w_k x[nl_k] (from LDS), then
// y @ VV cooperatively (VV is L2-hot) -- no xVV array, no 3rd gather.
__global__ __launch_bounds__(64, 5) void node_attn(
    const int* __restrict__ nlist,
    const float* __restrict__ G,
    const float* __restrict__ u,
    const float* __restrict__ xV,
    const float* __restrict__ VVm,
    float* __restrict__ outp, int n)
{
    __shared__ __align__(16) float Bs[2048];   // 16 rows x 128 floats (line-permuted)
    __shared__ __align__(16) float Ts[16];
    __shared__ __align__(16) float Ys[128];

    const int l  = threadIdx.x;   // 0..63
    const int g  = l >> 2;        // row/group 0..15
    const int jj = l & 3;         // 32-float chunk
    const int i  = blockIdx.x;

    int nlv = 0;
    if (l < 16) nlv = nlist[(size_t)i * 16 + l];
    unsigned long long mb = __ballot(l < 16 ? (nlv != n - 1) : 0);

    // async gather x-half of G[nl] -> LDS (8 instrs, 2 rows each)
    {
        int sub   = l & 31;                          // LDS line within row
        int sigma = ((sub & 3) << 3) | (sub >> 2);   // global line it must hold
        int half  = l >> 5;
        #pragma unroll
        for (int p = 0; p < 8; ++p) {
            int nr = __shfl(nlv, 2 * p + half, 64);
            const float* src = &G[(size_t)nr * 256 + sigma * 4];
            __builtin_amdgcn_global_load_lds(
                (const __attribute__((address_space(1))) unsigned int*)src,
                (__attribute__((address_space(3))) unsigned int*)&Bs[p * 256],
                16, 0, 0);
        }
    }

    // s200 = xQK[i] . x[i] while the gather is in flight
    float2 qa = *reinterpret_cast<const float2*>(&G[(size_t)i * 256 + 128 + l * 2]);
    float2 xa = *reinterpret_cast<const float2*>(&G[(size_t)i * 256 + l * 2]);
    float s200 = qa.x * xa.x + qa.y * xa.y;
    s200 = dpp_add<DPP_XOR1>(s200);
    s200 = dpp_add<DPP_XOR2>(s200);
    s200 = dpp_add<DPP_XOR7>(s200);
    s200 = dpp_add<DPP_XOR15>(s200);
    s200 += __shfl_xor(s200, 16, 64);
    s200 += __shfl_xor(s200, 32, 64);

    // A = xQK[nl_g] chunk jj (k-ascending), overlaps the gather
    int nl_g = __shfl(nlv, g, 64);
    float4 A[8];
    {
        const float* ab = &G[(size_t)nl_g * 256 + 128 + jj * 32];
        #pragma unroll
        for (int k4 = 0; k4 < 8; ++k4)
            A[k4] = *reinterpret_cast<const float4*>(&ab[k4 * 4]);
    }

    wave_vm_fence();

    // stage-1: sc[c] = xQK[nl_g] . x[nl_c]; leaky -> mask -> *scare -> row softmax
    float a[16];
    {
        float sc[16];
        #pragma unroll
        for (int c = 0; c < 16; ++c) {
            const float* bb = &Bs[c * 128 + jj * 4];
            float acc = 0.f;
            #pragma unroll
            for (int k4 = 0; k4 < 8; ++k4) {
                float4 b = *reinterpret_cast<const float4*>(&bb[k4 * 16]);
                acc += A[k4].x * b.x + A[k4].y * b.y + A[k4].z * b.z + A[k4].w * b.w;
            }
            acc = dpp_add<DPP_XOR1>(acc);
            acc = dpp_add<DPP_XOR2>(acc);
            sc[c] = acc;
        }
        bool rlive = (mb >> g) & 1ULL;
        float m = -3.0e38f;
        #pragma unroll
        for (int c = 0; c < 16; ++c) {
            float s = sc[c];
            float slr = s > 0.f ? s : 0.01f * s;
            bool live = rlive && ((mb >> c) & 1ULL);
            float sm = (live ? slr : NEG_CONST) * SCARE;
            sc[c] = sm;
            m = fmaxf(m, sm);
        }
        float ssum = 0.f;
        #pragma unroll
        for (int c = 0; c < 16; ++c) { float p = __expf(sc[c] - m); a[c] = p; ssum += p; }
        float rs = 1.f / ssum;
        #pragma unroll
        for (int c = 0; c < 16; ++c) a[c] *= rs;
    }

    // t_g = u[i] . x[nl_g]  (k4 staggered by g to spread LDS banks)
    {
        float acc = 0.f;
        #pragma unroll
        for (int k4 = 0; k4 < 8; ++k4) {
            int kx = (k4 + g) & 7;
            float4 b  = *reinterpret_cast<const float4*>(&Bs[g * 128 + kx * 16 + jj * 4]);
            float4 uu = *reinterpret_cast<const float4*>(&u[(size_t)i * 128 + jj * 32 + kx * 4]);
            acc += uu.x * b.x + uu.y * b.y + uu.z * b.z + uu.w * b.w;
        }
        acc = dpp_add<DPP_XOR1>(acc);
        acc = dpp_add<DPP_XOR2>(acc);
        if (jj == 0) Ts[g] = acc;
    }
    wave_lds_fence();
    float tarr[16];
    {
        #pragma unroll
        for (int q4 = 0; q4 < 4; ++q4) {
            float4 t4 = *reinterpret_cast<const float4*>(&Ts[q4 * 4]);
            tarr[q4 * 4 + 0] = t4.x; tarr[q4 * 4 + 1] = t4.y;
            tarr[q4 * 4 + 2] = t4.z; tarr[q4 * 4 + 3] = t4.w;
        }
    }

    // stage-2 logit for this group (j = g+1): scare -> leaky -> mask
    float lg = 0.f;
    #pragma unroll
    for (int k = 0; k < 16; ++k) lg += a[k] * tarr[k];
    {
        float v = lg * SCARE;
        v = v > 0.f ? v : 0.01f * v;
        lg = ((mb >> g) & 1ULL) ? v : NEG_CONST;
    }
    float v0 = s200 * SCARE;
    v0 = v0 > 0.f ? v0 : 0.01f * v0;

    float m17 = lg;
    m17 = dpp_max<DPP_XOR7>(m17);
    m17 = dpp_max<DPP_XOR15>(m17);
    m17 = fmaxf(m17, __shfl_xor(m17, 16, 64));
    m17 = fmaxf(m17, __shfl_xor(m17, 32, 64));
    m17 = fmaxf(m17, v0);
    float pg = __expf(lg - m17);
    float sg = pg;
    sg = dpp_add<DPP_XOR7>(sg);
    sg = dpp_add<DPP_XOR15>(sg);
    sg += __shfl_xor(sg, 16, 64);
    sg += __shfl_xor(sg, 32, 64);
    float p0 = __expf(v0 - m17);
    float inv = 1.f / (sg + p0);
    float a2g = pg * inv;   // a2[g+1] (replicated within quad)
    float a20 = p0 * inv;

    // w[k] = sum_g a2[g+1] * a[g][k]
    float w[16];
    #pragma unroll
    for (int k = 0; k < 16; ++k) {
        float wv = a2g * a[k];
        wv = dpp_add<DPP_XOR7>(wv);
        wv = dpp_add<DPP_XOR15>(wv);
        wv += __shfl_xor(wv, 16, 64);
        wv += __shfl_xor(wv, 32, 64);
        w[k] = wv;
    }

    // y = sum_k w[k] * x[nl_k]  -- this lane's 2 elements (h = 2l, 2l+1) from LDS
    {
        int sg2 = l >> 1;                            // global 16B-line of element 2l
        int tau = ((sg2 & 7) << 2) | (sg2 >> 3);     // LDS line holding it
        int off2 = (2 * l) & 3;
        float y0 = 0.f, y1 = 0.f;
        #pragma unroll
        for (int k = 0; k < 16; ++k) {
            const float* bp = &Bs[k * 128 + tau * 4 + off2];
            y0 += w[k] * bp[0];
            y1 += w[k] * bp[1];
        }
        float2 ywr = {y0, y1};
        *reinterpret_cast<float2*>(&Ys[2 * l]) = ywr;
    }
    wave_lds_fence();

    // out_gather = y @ VV : lane (g,jj) computes h-range [8g,8g+8) over k-chunk jj
    float p8[8] = {};
    {
        float4 ys[8];
        #pragma unroll
        for (int q = 0; q < 8; ++q)
            ys[q] = *reinterpret_cast<const float4*>(&Ys[jj * 32 + q * 4]);
        #pragma unroll
        for (int q = 0; q < 8; ++q) {
            float yv[4] = {ys[q].x, ys[q].y, ys[q].z, ys[q].w};
            #pragma unroll
            for (int e = 0; e < 4; ++e) {
                int kidx = jj * 32 + q * 4 + e;
                const float* row = &VVm[kidx * 128 + 8 * g];
                float4 va = *reinterpret_cast<const float4*>(row);
                float4 vb = *reinterpret_cast<const float4*>(row + 4);
                float yk = yv[e];
                p8[0] += yk * va.x; p8[1] += yk * va.y;
                p8[2] += yk * va.z; p8[3] += yk * va.w;
                p8[4] += yk * vb.x; p8[5] += yk * vb.y;
                p8[6] += yk * vb.z; p8[7] += yk * vb.w;
            }
        }
        #pragma unroll
        for (int m = 0; m < 8; ++m) {
            p8[m] = dpp_add<DPP_XOR1>(p8[m]);
            p8[m] = dpp_add<DPP_XOR2>(p8[m]);
        }
    }
    // my output pair h = 8g+2jj (== 2l), 8g+2jj+1: select by jj
    float gp0 = (jj == 0) ? p8[0] : (jj == 1) ? p8[2] : (jj == 2) ? p8[4] : p8[6];
    float gp1 = (jj == 0) ? p8[1] : (jj == 1) ? p8[3] : (jj == 2) ? p8[5] : p8[7];

    float2 xv = *reinterpret_cast<const float2*>(&xV[(size_t)i * 128 + l * 2]);
    float o0 = a20 * xv.x + gp0;
    float o1 = a20 * xv.y + gp1;
    float sq = o0 * o0 + o1 * o1;
    sq = dpp_add<DPP_XOR1>(sq);
    sq = dpp_add<DPP_XOR2>(sq);
    sq = dpp_add<DPP_XOR7>(sq);
    sq = dpp_add<DPP_XOR15>(sq);
    sq += __shfl_xor(sq, 16, 64);
    sq += __shfl_xor(sq, 32, 64);
    float d = fmaxf(sqrtf(sq), 1e-12f);
    float rd = 1.f / d;
    float2 o = {o0 * rd, o1 * rd};
    *reinterpret_cast<float2*>(&outp[(size_t)i * 128 + l * 2]) = o;
}

extern "C" void kernel_launch(void* const* d_in, const int* in_sizes, int n_in,
                              void* d_out, int out_size, void* d_ws, size_t ws_size,
                              hipStream_t stream) {
    const float* x     = (const float*)d_in[0];
    const int*   nlist = (const int*)d_in[1];
    const float* Q     = (const float*)d_in[2];
    const float* K     = (const float*)d_in[3];
    const float* V     = (const float*)d_in[4];
    float* out = (float*)d_out;
    int n = in_sizes[0] / 128;   // 50000

    float* ws   = (float*)d_ws;
    float* QKt  = ws;                  // 16384
    float* MT   = ws + 16384;          // 16384
    float* VV   = ws + 32768;          // 16384
    float* G    = ws + 49152;          // n*256
    float* uarr = G + (size_t)n * 256;
    float* xV   = uarr + (size_t)n * 128;

    small_mm_a<<<dim3(16, 2), 256, 0, stream>>>(Q, K, V, QKt, VV);
    small_mm_b<<<dim3(16), 256, 0, stream>>>(QKt, V, MT);
    dim3 g2((n + 127) / 128, 3);
    proj_gemm<<<g2, 256, 0, stream>>>(x, QKt, MT, V, G, uarr, xV, n);
    node_attn<<<n, 64, 0, stream>>>(nlist, G, uarr, xV, VV, out, n);
}

// Round 7
// 299.114 us; speedup vs baseline: 1.9882x; 1.9882x over previous
//
#include <hip/hip_runtime.h>
#include <math.h>

#define NEG_CONST (-9000000000000000.0f)
#define SCARE 11.313708498984761f  // sqrt(128)

#define DPP_XOR1  0xB1   // quad_perm [1,0,3,2]
#define DPP_XOR2  0x4E   // quad_perm [2,3,0,1]
#define DPP_XOR7  0x141  // row_half_mirror
#define DPP_XOR15 0x140  // row_mirror

template<int CTRL>
__device__ __forceinline__ float dpp_add(float x) {
    int yi = __builtin_amdgcn_update_dpp(0, __float_as_int(x), CTRL, 0xF, 0xF, true);
    return x + __int_as_float(yi);
}
template<int CTRL>
__device__ __forceinline__ float dpp_max(float x) {
    int yi = __builtin_amdgcn_update_dpp(0, __float_as_int(x), CTRL, 0xF, 0xF, true);
    return fmaxf(x, __int_as_float(yi));
}

__device__ __forceinline__ void wave_lds_fence() {
    __builtin_amdgcn_wave_barrier();
    asm volatile("s_waitcnt lgkmcnt(0)" ::: "memory");
    __builtin_amdgcn_wave_barrier();
}
__device__ __forceinline__ void wave_vm_fence() {
    __builtin_amdgcn_wave_barrier();
    asm volatile("s_waitcnt vmcnt(0) lgkmcnt(0)" ::: "memory");
    __builtin_amdgcn_wave_barrier();
}

// ---- kernel 1: y=0: QKt = Q @ K^T ; y=1: VV = V @ V  (grid (16,2)) ----
__global__ __launch_bounds__(256) void small_mm_a(const float* __restrict__ Q,
                                                  const float* __restrict__ K,
                                                  const float* __restrict__ V,
                                                  float* __restrict__ QKt,
                                                  float* __restrict__ VV) {
    int r  = blockIdx.x * 8 + (threadIdx.x >> 5);
    int c0 = (threadIdx.x & 31) * 4;
    float a0 = 0.f, a1 = 0.f, a2 = 0.f, a3 = 0.f;
    if (blockIdx.y == 0) {
        for (int k = 0; k < 128; k += 4) {
            float4 q  = *reinterpret_cast<const float4*>(&Q[r * 128 + k]);
            float4 k0 = *reinterpret_cast<const float4*>(&K[(c0 + 0) * 128 + k]);
            float4 k1 = *reinterpret_cast<const float4*>(&K[(c0 + 1) * 128 + k]);
            float4 k2 = *reinterpret_cast<const float4*>(&K[(c0 + 2) * 128 + k]);
            float4 k3 = *reinterpret_cast<const float4*>(&K[(c0 + 3) * 128 + k]);
            a0 += q.x*k0.x + q.y*k0.y + q.z*k0.z + q.w*k0.w;
            a1 += q.x*k1.x + q.y*k1.y + q.z*k1.z + q.w*k1.w;
            a2 += q.x*k2.x + q.y*k2.y + q.z*k2.z + q.w*k2.w;
            a3 += q.x*k3.x + q.y*k3.y + q.z*k3.z + q.w*k3.w;
        }
        float4 o = {a0, a1, a2, a3};
        *reinterpret_cast<float4*>(&QKt[r * 128 + c0]) = o;
    } else {
        for (int k = 0; k < 128; ++k) {
            float a = V[r * 128 + k];
            float4 b = *reinterpret_cast<const float4*>(&V[k * 128 + c0]);
            a0 += a * b.x; a1 += a * b.y; a2 += a * b.z; a3 += a * b.w;
        }
        float4 o = {a0, a1, a2, a3};
        *reinterpret_cast<float4*>(&VV[r * 128 + c0]) = o;
    }
}

// ---- kernel 2: MT = QKt @ V^T  (grid 16) ----
__global__ __launch_bounds__(256) void small_mm_b(const float* __restrict__ QKt,
                                                  const float* __restrict__ V,
                                                  float* __restrict__ MT) {
    int r  = blockIdx.x * 8 + (threadIdx.x >> 5);
    int c0 = (threadIdx.x & 31) * 4;
    float a0 = 0.f, a1 = 0.f, a2 = 0.f, a3 = 0.f;
    for (int k = 0; k < 128; k += 4) {
        float4 q  = *reinterpret_cast<const float4*>(&QKt[r * 128 + k]);
        float4 k0 = *reinterpret_cast<const float4*>(&V[(c0 + 0) * 128 + k]);
        float4 k1 = *reinterpret_cast<const float4*>(&V[(c0 + 1) * 128 + k]);
        float4 k2 = *reinterpret_cast<const float4*>(&V[(c0 + 2) * 128 + k]);
        float4 k3 = *reinterpret_cast<const float4*>(&V[(c0 + 3) * 128 + k]);
        a0 += q.x*k0.x + q.y*k0.y + q.z*k0.z + q.w*k0.w;
        a1 += q.x*k1.x + q.y*k1.y + q.z*k1.z + q.w*k1.w;
        a2 += q.x*k2.x + q.y*k2.y + q.z*k2.z + q.w*k2.w;
        a3 += q.x*k3.x + q.y*k3.y + q.z*k3.z + q.w*k3.w;
    }
    float4 o = {a0, a1, a2, a3};
    *reinterpret_cast<float4*>(&MT[r * 128 + c0]) = o;
}

// ---- kernel 3: projections; y=0: G[:,128:256]=x@QKt (+pack x into G[:,0:128]);
//      y=1: u=x@MT; y=2: xV=x@V.  128x128 tile, 8x8 per thread ----
__global__ __launch_bounds__(256) void proj_gemm(
    const float* __restrict__ x,
    const float* __restrict__ W0, const float* __restrict__ W1,
    const float* __restrict__ W2,
    float* __restrict__ G, float* __restrict__ O1, float* __restrict__ O2,
    int n)
{
    __shared__ __align__(16) float xs[32][132];  // [k][row] (transposed)
    __shared__ __align__(16) float ws[32][132];  // [k][col]

    const float* Wsel[3] = {W0, W1, W2};
    float*       Osel[3] = {G, O1, O2};
    const int    osr[3]  = {256, 128, 128};
    const int    oof[3]  = {128, 0, 0};
    int yb = blockIdx.y;
    const float* W = Wsel[yb];
    float*       O = Osel[yb];
    int ostride = osr[yb];
    int ooff = oof[yb];
    int row0 = blockIdx.x * 128;
    int tid = threadIdx.x;
    int tr = tid >> 4, tc = tid & 15;

    float acc[8][8] = {};
    for (int kk = 0; kk < 128; kk += 32) {
        #pragma unroll
        for (int it = 0; it < 4; ++it) {
            int id = tid + it * 256;
            int r = id >> 3;
            int f = id & 7;
            int grow = row0 + r;
            float4 v = (grow < n)
                ? *reinterpret_cast<const float4*>(&x[(size_t)grow * 128 + kk + f * 4])
                : make_float4(0.f, 0.f, 0.f, 0.f);
            xs[f * 4 + 0][r] = v.x; xs[f * 4 + 1][r] = v.y;
            xs[f * 4 + 2][r] = v.z; xs[f * 4 + 3][r] = v.w;
            if (yb == 0 && grow < n)
                *reinterpret_cast<float4*>(&G[(size_t)grow * 256 + kk + f * 4]) = v;
        }
        #pragma unroll
        for (int it = 0; it < 4; ++it) {
            int id = tid + it * 256;
            int k = id >> 5;
            int c4 = id & 31;
            *reinterpret_cast<float4*>(&ws[k][c4 * 4]) =
                *reinterpret_cast<const float4*>(&W[(size_t)(kk + k) * 128 + c4 * 4]);
        }
        __syncthreads();
        #pragma unroll 4
        for (int k = 0; k < 32; ++k) {
            float4 a0 = *reinterpret_cast<const float4*>(&xs[k][tr * 8]);
            float4 a1 = *reinterpret_cast<const float4*>(&xs[k][tr * 8 + 4]);
            float4 b0 = *reinterpret_cast<const float4*>(&ws[k][tc * 8]);
            float4 b1 = *reinterpret_cast<const float4*>(&ws[k][tc * 8 + 4]);
            float av[8] = {a0.x, a0.y, a0.z, a0.w, a1.x, a1.y, a1.z, a1.w};
            float bv[8] = {b0.x, b0.y, b0.z, b0.w, b1.x, b1.y, b1.z, b1.w};
            #pragma unroll
            for (int i2 = 0; i2 < 8; ++i2)
                #pragma unroll
                for (int j2 = 0; j2 < 8; ++j2)
                    acc[i2][j2] += av[i2] * bv[j2];
        }
        __syncthreads();
    }
    #pragma unroll
    for (int i2 = 0; i2 < 8; ++i2) {
        int grow = row0 + tr * 8 + i2;
        if (grow < n) {
            float4 o0 = {acc[i2][0], acc[i2][1], acc[i2][2], acc[i2][3]};
            float4 o1 = {acc[i2][4], acc[i2][5], acc[i2][6], acc[i2][7]};
            *reinterpret_cast<float4*>(&O[(size_t)grow * ostride + ooff + tc * 8])     = o0;
            *reinterpret_cast<float4*>(&O[(size_t)grow * ostride + ooff + tc * 8 + 4]) = o1;
        }
    }
}

// ---- kernel 4: per-node attention, 1 WAVE = 1 BLOCK = 1 node ----
// G[i] = [x[i](128) | xQK[i](128)] -> each neighbor gather is 1KB contiguous.
// Writes y_i = sum_k w_k x[nl_k] (over u's buffer; u[i] is consumed first,
// same block only) and c0_i = a2_0. Dense epilogue handles y@VV + normalize.
__global__ __launch_bounds__(64, 5) void node_attn(
    const int* __restrict__ nlist,
    const float* __restrict__ G,
    float* uy,                      // in: u = x@MT ; out: y (aliased)
    float* __restrict__ c0a,
    int n)
{
    __shared__ __align__(16) float Bs[2048];   // 16 rows x 128 floats (line-permuted)
    __shared__ __align__(16) float Ts[16];

    const int l  = threadIdx.x;   // 0..63
    const int g  = l >> 2;        // row/group 0..15
    const int jj = l & 3;         // 32-float chunk
    const int i  = blockIdx.x;

    int nlv = 0;
    if (l < 16) nlv = nlist[(size_t)i * 16 + l];
    unsigned long long mb = __ballot(l < 16 ? (nlv != n - 1) : 0);

    // async gather x-half of G[nl] -> LDS (8 instrs, 2 rows each)
    {
        int sub   = l & 31;                          // LDS line within row
        int sigma = ((sub & 3) << 3) | (sub >> 2);   // global line it must hold
        int half  = l >> 5;
        #pragma unroll
        for (int p = 0; p < 8; ++p) {
            int nr = __shfl(nlv, 2 * p + half, 64);
            const float* src = &G[(size_t)nr * 256 + sigma * 4];
            __builtin_amdgcn_global_load_lds(
                (const __attribute__((address_space(1))) unsigned int*)src,
                (__attribute__((address_space(3))) unsigned int*)&Bs[p * 256],
                16, 0, 0);
        }
    }

    // s200 = xQK[i] . x[i] while the gather is in flight
    float2 qa = *reinterpret_cast<const float2*>(&G[(size_t)i * 256 + 128 + l * 2]);
    float2 xa = *reinterpret_cast<const float2*>(&G[(size_t)i * 256 + l * 2]);
    float s200 = qa.x * xa.x + qa.y * xa.y;
    s200 = dpp_add<DPP_XOR1>(s200);
    s200 = dpp_add<DPP_XOR2>(s200);
    s200 = dpp_add<DPP_XOR7>(s200);
    s200 = dpp_add<DPP_XOR15>(s200);
    s200 += __shfl_xor(s200, 16, 64);
    s200 += __shfl_xor(s200, 32, 64);

    // A = xQK[nl_g] chunk jj (k-ascending), overlaps the gather
    int nl_g = __shfl(nlv, g, 64);
    float4 A[8];
    {
        const float* ab = &G[(size_t)nl_g * 256 + 128 + jj * 32];
        #pragma unroll
        for (int k4 = 0; k4 < 8; ++k4)
            A[k4] = *reinterpret_cast<const float4*>(&ab[k4 * 4]);
    }

    wave_vm_fence();

    // stage-1: sc[c] = xQK[nl_g] . x[nl_c]; leaky -> mask -> *scare -> row softmax
    float a[16];
    {
        float sc[16];
        #pragma unroll
        for (int c = 0; c < 16; ++c) {
            const float* bb = &Bs[c * 128 + jj * 4];
            float acc = 0.f;
            #pragma unroll
            for (int k4 = 0; k4 < 8; ++k4) {
                float4 b = *reinterpret_cast<const float4*>(&bb[k4 * 16]);
                acc += A[k4].x * b.x + A[k4].y * b.y + A[k4].z * b.z + A[k4].w * b.w;
            }
            acc = dpp_add<DPP_XOR1>(acc);
            acc = dpp_add<DPP_XOR2>(acc);
            sc[c] = acc;
        }
        bool rlive = (mb >> g) & 1ULL;
        float m = -3.0e38f;
        #pragma unroll
        for (int c = 0; c < 16; ++c) {
            float s = sc[c];
            float slr = s > 0.f ? s : 0.01f * s;
            bool live = rlive && ((mb >> c) & 1ULL);
            float sm = (live ? slr : NEG_CONST) * SCARE;
            sc[c] = sm;
            m = fmaxf(m, sm);
        }
        float ssum = 0.f;
        #pragma unroll
        for (int c = 0; c < 16; ++c) { float p = __expf(sc[c] - m); a[c] = p; ssum += p; }
        float rs = 1.f / ssum;
        #pragma unroll
        for (int c = 0; c < 16; ++c) a[c] *= rs;
    }

    // t_g = u[i] . x[nl_g]  (k4 staggered by g to spread LDS banks)
    {
        float acc = 0.f;
        #pragma unroll
        for (int k4 = 0; k4 < 8; ++k4) {
            int kx = (k4 + g) & 7;
            float4 b  = *reinterpret_cast<const float4*>(&Bs[g * 128 + kx * 16 + jj * 4]);
            float4 uu = *reinterpret_cast<const float4*>(&uy[(size_t)i * 128 + jj * 32 + kx * 4]);
            acc += uu.x * b.x + uu.y * b.y + uu.z * b.z + uu.w * b.w;
        }
        acc = dpp_add<DPP_XOR1>(acc);
        acc = dpp_add<DPP_XOR2>(acc);
        if (jj == 0) Ts[g] = acc;
    }
    wave_lds_fence();
    float tarr[16];
    {
        #pragma unroll
        for (int q4 = 0; q4 < 4; ++q4) {
            float4 t4 = *reinterpret_cast<const float4*>(&Ts[q4 * 4]);
            tarr[q4 * 4 + 0] = t4.x; tarr[q4 * 4 + 1] = t4.y;
            tarr[q4 * 4 + 2] = t4.z; tarr[q4 * 4 + 3] = t4.w;
        }
    }

    // stage-2 logit for this group (j = g+1): scare -> leaky -> mask
    float lg = 0.f;
    #pragma unroll
    for (int k = 0; k < 16; ++k) lg += a[k] * tarr[k];
    {
        float v = lg * SCARE;
        v = v > 0.f ? v : 0.01f * v;
        lg = ((mb >> g) & 1ULL) ? v : NEG_CONST;
    }
    float v0 = s200 * SCARE;
    v0 = v0 > 0.f ? v0 : 0.01f * v0;

    float m17 = lg;
    m17 = dpp_max<DPP_XOR7>(m17);
    m17 = dpp_max<DPP_XOR15>(m17);
    m17 = fmaxf(m17, __shfl_xor(m17, 16, 64));
    m17 = fmaxf(m17, __shfl_xor(m17, 32, 64));
    m17 = fmaxf(m17, v0);
    float pg = __expf(lg - m17);
    float sg = pg;
    sg = dpp_add<DPP_XOR7>(sg);
    sg = dpp_add<DPP_XOR15>(sg);
    sg += __shfl_xor(sg, 16, 64);
    sg += __shfl_xor(sg, 32, 64);
    float p0 = __expf(v0 - m17);
    float inv = 1.f / (sg + p0);
    float a2g = pg * inv;   // a2[g+1] (replicated within quad)
    float a20 = p0 * inv;

    // w[k] = sum_g a2[g+1] * a[g][k]
    float w[16];
    #pragma unroll
    for (int k = 0; k < 16; ++k) {
        float wv = a2g * a[k];
        wv = dpp_add<DPP_XOR7>(wv);
        wv = dpp_add<DPP_XOR15>(wv);
        wv += __shfl_xor(wv, 16, 64);
        wv += __shfl_xor(wv, 32, 64);
        w[k] = wv;
    }

    // y = sum_k w[k] * x[nl_k]; lane owns h = 2l,2l+1. The 64 float2 reads tile
    // the full 512B LDS row -> perfectly distributed banks, 0 conflicts.
    {
        int sg2 = l >> 1;                            // global 16B-line of element 2l
        int tau = ((sg2 & 7) << 2) | (sg2 >> 3);     // LDS line holding it
        int off2 = (2 * l) & 3;
        float y0 = 0.f, y1 = 0.f;
        #pragma unroll
        for (int k = 0; k < 16; ++k) {
            float2 bp = *reinterpret_cast<const float2*>(&Bs[k * 128 + tau * 4 + off2]);
            y0 += w[k] * bp.x;
            y1 += w[k] * bp.y;
        }
        float2 yw = {y0, y1};
        *reinterpret_cast<float2*>(&uy[(size_t)i * 128 + 2 * l]) = yw;
    }
    if (l == 0) c0a[i] = a20;
}

// ---- kernel 5: epilogue GEMM: out = normalize(c0*xV + y@VV), 128x128 tile ----
__global__ __launch_bounds__(256) void ep_gemm(
    const float* __restrict__ y, const float* __restrict__ xV,
    const float* __restrict__ c0a, const float* __restrict__ VVm,
    float* __restrict__ outp, int n)
{
    __shared__ __align__(16) float ysd[32][132];  // [k][row] (transposed)
    __shared__ __align__(16) float wsd[32][132];  // [k][col]

    int row0 = blockIdx.x * 128;
    int tid = threadIdx.x;
    int tr = tid >> 4, tc = tid & 15;

    float acc[8][8] = {};
    for (int kk = 0; kk < 128; kk += 32) {
        #pragma unroll
        for (int it = 0; it < 4; ++it) {
            int id = tid + it * 256;
            int r = id >> 3;
            int f = id & 7;
            int grow = row0 + r;
            float4 v = (grow < n)
                ? *reinterpret_cast<const float4*>(&y[(size_t)grow * 128 + kk + f * 4])
                : make_float4(0.f, 0.f, 0.f, 0.f);
            ysd[f * 4 + 0][r] = v.x; ysd[f * 4 + 1][r] = v.y;
            ysd[f * 4 + 2][r] = v.z; ysd[f * 4 + 3][r] = v.w;
        }
        #pragma unroll
        for (int it = 0; it < 4; ++it) {
            int id = tid + it * 256;
            int k = id >> 5;
            int c4 = id & 31;
            *reinterpret_cast<float4*>(&wsd[k][c4 * 4]) =
                *reinterpret_cast<const float4*>(&VVm[(size_t)(kk + k) * 128 + c4 * 4]);
        }
        __syncthreads();
        #pragma unroll 4
        for (int k = 0; k < 32; ++k) {
            float4 a0 = *reinterpret_cast<const float4*>(&ysd[k][tr * 8]);
            float4 a1 = *reinterpret_cast<const float4*>(&ysd[k][tr * 8 + 4]);
            float4 b0 = *reinterpret_cast<const float4*>(&wsd[k][tc * 8]);
            float4 b1 = *reinterpret_cast<const float4*>(&wsd[k][tc * 8 + 4]);
            float av[8] = {a0.x, a0.y, a0.z, a0.w, a1.x, a1.y, a1.z, a1.w};
            float bv[8] = {b0.x, b0.y, b0.z, b0.w, b1.x, b1.y, b1.z, b1.w};
            #pragma unroll
            for (int i2 = 0; i2 < 8; ++i2)
                #pragma unroll
                for (int j2 = 0; j2 < 8; ++j2)
                    acc[i2][j2] += av[i2] * bv[j2];
        }
        __syncthreads();
    }

    // per-row: add c0*xV, L2-normalize across the 16 tc-lanes (DPP 16-lane sum)
    #pragma unroll
    for (int i2 = 0; i2 < 8; ++i2) {
        int grow = row0 + tr * 8 + i2;
        float c0v = 0.f;
        float4 xv0 = make_float4(0.f, 0.f, 0.f, 0.f);
        float4 xv1 = make_float4(0.f, 0.f, 0.f, 0.f);
        if (grow < n) {
            c0v = c0a[grow];
            xv0 = *reinterpret_cast<const float4*>(&xV[(size_t)grow * 128 + tc * 8]);
            xv1 = *reinterpret_cast<const float4*>(&xV[(size_t)grow * 128 + tc * 8 + 4]);
        }
        float o[8];
        o[0] = acc[i2][0] + c0v * xv0.x; o[1] = acc[i2][1] + c0v * xv0.y;
        o[2] = acc[i2][2] + c0v * xv0.z; o[3] = acc[i2][3] + c0v * xv0.w;
        o[4] = acc[i2][4] + c0v * xv1.x; o[5] = acc[i2][5] + c0v * xv1.y;
        o[6] = acc[i2][6] + c0v * xv1.z; o[7] = acc[i2][7] + c0v * xv1.w;
        float ss = 0.f;
        #pragma unroll
        for (int j2 = 0; j2 < 8; ++j2) ss += o[j2] * o[j2];
        ss = dpp_add<DPP_XOR1>(ss);
        ss = dpp_add<DPP_XOR2>(ss);
        ss = dpp_add<DPP_XOR7>(ss);
        ss = dpp_add<DPP_XOR15>(ss);
        float d = fmaxf(sqrtf(ss), 1e-12f);
        float rd = 1.f / d;
        if (grow < n) {
            float4 o0 = {o[0] * rd, o[1] * rd, o[2] * rd, o[3] * rd};
            float4 o1 = {o[4] * rd, o[5] * rd, o[6] * rd, o[7] * rd};
            *reinterpret_cast<float4*>(&outp[(size_t)grow * 128 + tc * 8])     = o0;
            *reinterpret_cast<float4*>(&outp[(size_t)grow * 128 + tc * 8 + 4]) = o1;
        }
    }
}

extern "C" void kernel_launch(void* const* d_in, const int* in_sizes, int n_in,
                              void* d_out, int out_size, void* d_ws, size_t ws_size,
                              hipStream_t stream) {
    const float* x     = (const float*)d_in[0];
    const int*   nlist = (const int*)d_in[1];
    const float* Q     = (const float*)d_in[2];
    const float* K     = (const float*)d_in[3];
    const float* V     = (const float*)d_in[4];
    float* out = (float*)d_out;
    int n = in_sizes[0] / 128;   // 50000

    float* ws   = (float*)d_ws;
    float* QKt  = ws;                    // 16384
    float* MT   = ws + 16384;            // 16384
    float* VV   = ws + 32768;            // 16384
    float* c0a  = ws + 49152;            // n
    float* G    = c0a + n;               // n*256
    float* uarr = G + (size_t)n * 256;   // n*128  (y aliases this after node_attn)
    float* xV   = uarr + (size_t)n * 128;// n*128

    small_mm_a<<<dim3(16, 2), 256, 0, stream>>>(Q, K, V, QKt, VV);
    small_mm_b<<<dim3(16), 256, 0, stream>>>(QKt, V, MT);
    dim3 g2((n + 127) / 128, 3);
    proj_gemm<<<g2, 256, 0, stream>>>(x, QKt, MT, V, G, uarr, xV, n);
    node_attn<<<n, 64, 0, stream>>>(nlist, G, uarr, c0a, n);
    ep_gemm<<<(n + 127) / 128, 256, 0, stream>>>(uarr, xV, c0a, VV, out, n);
}